// Round 10
// baseline (215.809 us; speedup 1.0000x reference)
//
#include <hip/hip_runtime.h>

#define DM 1024
#define NW 16384

typedef __attribute__((ext_vector_type(8))) short short8;
typedef __attribute__((ext_vector_type(4))) float f32x4;

// ws layout (float offsets). High-water = OFF_PART + 512*16*1024 = 8437760 floats
// (~32.2 MiB) — fits the ws buffer (256 MiB poison fills observed in rocprof).
#define OFF_AH   1024       // A-frag hi: 16384 shorts = 8192 floats
#define OFF_AL   9216       // A-frag lo: 16384 shorts
#define OFF_D0   17408      // 16
#define OFF_SP   17440      // Spart[16][512] = 8192
#define OFF_X    25632      // 1024
#define OFF_W    26656      // 16384 -> ends 43040
#define OFF_PART 49152      // part[512][16][1024] = 8388608 floats

// fp32 -> bf16 round-to-nearest-even (returns bits)
__device__ __forceinline__ unsigned short f2bf(float f) {
  unsigned int u = __float_as_uint(f);
  return (unsigned short)((u + 0x7fffu + ((u >> 16) & 1u)) >> 16);
}

#define WAITV(N) asm volatile("s_waitcnt vmcnt(" #N ")" ::: "memory")
#define SB() __builtin_amdgcn_sched_barrier(0)
#define BAR() { __builtin_amdgcn_s_barrier(); __builtin_amdgcn_sched_barrier(0); }

// out[r] = dot(W[r,:], v) + b[r]   — one wave per row, 1024 waves
__global__ __launch_bounds__(256) void k_rowdot(const float* __restrict__ W,
                                                const float* __restrict__ v,
                                                const float* __restrict__ b,
                                                float* __restrict__ out) {
  const int wave = (blockIdx.x * 256 + threadIdx.x) >> 6;
  const int lane = threadIdx.x & 63;
  const float* row = W + (size_t)wave * DM + 4 * lane;
  float s = 0.f;
#pragma unroll
  for (int j = 0; j < 4; ++j) {
    float4 a = *(const float4*)(row + j * 256);
    float4 x = *(const float4*)(v + j * 256 + 4 * lane);
    s += a.x * x.x + a.y * x.y + a.z * x.z + a.w * x.w;
  }
#pragma unroll
  for (int off = 32; off; off >>= 1) s += __shfl_xor(s, off, 64);
  if (lane == 0) out[wave] = s + b[wave];
}

// Fused: q_h = query@Wq_h^T + bq (LDS), then c[h,m] = q_h · Wk[h*64+:,m],
// emitted directly as MFMA A-fragments (bf16 hi+lo). d0[h] = q_h·bk_h.
// Also zeroes w (16384 floats) for k_wred's atomics.
__global__ __launch_bounds__(256) void k_qck(const float* __restrict__ Wq,
                                             const float* __restrict__ bq,
                                             const float* __restrict__ query,
                                             const float* __restrict__ Wk,
                                             const float* __restrict__ bk,
                                             short* __restrict__ Ah,
                                             short* __restrict__ Al,
                                             float* __restrict__ d0,
                                             float* __restrict__ w) {
  const int h = blockIdx.x >> 2;
  const int mc = blockIdx.x & 3;
  const int t = threadIdx.x;
  const int lane = t & 63;
  const int wv = t >> 6;
  __shared__ float qh[64];
  w[blockIdx.x * 256 + t] = 0.f;          // 64*256 = 16384 threads exactly
  float4 qv[4];
#pragma unroll
  for (int j = 0; j < 4; ++j) qv[j] = *(const float4*)(query + j * 256 + 4 * lane);
#pragma unroll 1
  for (int ii = 0; ii < 16; ii += 4) {
    float4 a[4][4];
#pragma unroll
    for (int r = 0; r < 4; ++r) {
      const float* rp = Wq + (size_t)(h * 64 + 4 * (ii + r) + wv) * DM + 4 * lane;
#pragma unroll
      for (int j = 0; j < 4; ++j) a[r][j] = *(const float4*)(rp + j * 256);
    }
    float s[4] = {0.f, 0.f, 0.f, 0.f};
#pragma unroll
    for (int r = 0; r < 4; ++r)
#pragma unroll
      for (int j = 0; j < 4; ++j)
        s[r] += a[r][j].x * qv[j].x + a[r][j].y * qv[j].y +
                a[r][j].z * qv[j].z + a[r][j].w * qv[j].w;
#pragma unroll
    for (int off = 32; off; off >>= 1)
#pragma unroll
      for (int r = 0; r < 4; ++r) s[r] += __shfl_xor(s[r], off, 64);
    if (lane == 0)
#pragma unroll
      for (int r = 0; r < 4; ++r)
        qh[4 * (ii + r) + wv] = s[r] + bq[h * 64 + 4 * (ii + r) + wv];
  }
  __syncthreads();
  const int m = mc * 256 + t;
  const float* Wp = Wk + (size_t)(h * 64) * DM + m;
  float s = 0.f;
#pragma unroll 2
  for (int db = 0; db < 8; ++db) {
    float wv8[8];
#pragma unroll
    for (int j = 0; j < 8; ++j) wv8[j] = Wp[(size_t)(db * 8 + j) * DM];
#pragma unroll
    for (int j = 0; j < 8; ++j) s = fmaf(qh[db * 8 + j], wv8[j], s);
  }
  unsigned short hu = f2bf(s);
  float hf = __uint_as_float(((unsigned int)hu) << 16);
  unsigned short lu = f2bf(s - hf);
  const int kb = m >> 5, q = (m >> 3) & 3, j = m & 7;
  const int idx = (kb * 64 + q * 16 + h) * 8 + j;
  Ah[idx] = (short)hu;
  Al[idx] = (short)lu;
  if (mc == 0 && t == 0) {
    float tt = 0.f;
    for (int d = 0; d < 64; ++d) tt += qh[d] * bk[h * 64 + d];
    d0[h] = tt;
  }
}

// Fused scores + PV. 512 blocks × 512 threads (8 waves), 2 blocks/CU.
// Phase A: key staged to LDS via global_load_lds (fire-and-forget — compiler
//   cannot collapse it), 8 slices of 32rows×512B (16 KB), 4 LDS buffers,
//   3-deep counted-vmcnt pipeline (steady-state vmcnt(8), never 0 until tail).
//   Source-side XOR swizzle (chunk ^= row&7) + same XOR on ds_read (T21
//   involution) kills the row-stride bank conflict. 8 waves = 2 tiles ×
//   4-way kb-split per slice; one barrier per slice.
// Phase B: thread owns cols 2t..2t+1, 2-deep double-buffered value loop.
__global__ __launch_bounds__(512, 4) void k_spv(const float* __restrict__ key,
                                                const float* __restrict__ value,
                                                const short* __restrict__ AhG,
                                                const short* __restrict__ AlG,
                                                const float* __restrict__ d0,
                                                float* __restrict__ part,
                                                float* __restrict__ Spart) {
  const int nb = blockIdx.x;              // 0..511 (32-row chunk)
  const int t = threadIdx.x;              // 0..511
  const int lane = t & 63;
  const int wv = t >> 6;                  // 0..7
  const int tile = wv >> 2;               // 0..1  -> 16-row tile
  const int kq = wv & 3;                  // kb within slice
  const int row16 = lane & 15;
  const int nl = tile * 16 + row16;       // local row 0..31
  const int quad = lane >> 4;
  const short8* A8h = (const short8*)AhG;
  const short8* A8l = (const short8*)AlG;

  __shared__ float kst[4][32 * 128];      // 64 KB: 4 key-slice buffers
  __shared__ float el[32 * 16];           // 2 KB
  __shared__ f32x4 sred[8][64];           // 8 KB

  const int slot0 = wv * 2;               // this wave stages rows 4wv..4wv+3
  // swizzled ds_read offsets (floats) — slice-invariant
  const int swz = nl & 7;
  const int c0 = kq * 8 + quad * 2;
  const int o0 = nl * 128 + ((c0 ^ swz) << 2);
  const int o1 = nl * 128 + (((c0 + 1) ^ swz) << 2);

  f32x4 acc0 = {0.f, 0.f, 0.f, 0.f};
  f32x4 acc1 = {0.f, 0.f, 0.f, 0.f};
  short8 a0h, a0l, a1h, a1l, a2h, a2l;

  // 2 global_load_lds per wave per slice: slot = wv*2+j stages rows 2slot,
  // 2slot+1. Lane l: row = 2slot + (l>>5), fetches global 16B-chunk
  // (l&31)^(row&7) -> LDS linear (HW: base + lane*16). Read undoes the XOR.
#define STAGE(S) { \
  _Pragma("unroll") for (int j = 0; j < 2; ++j) { \
    const int slot = slot0 + j; \
    const int row = 2 * slot + (lane >> 5); \
    const int ch = (lane & 31) ^ (row & 7); \
    const float* g = key + (size_t)(nb * 32 + row) * DM + (S) * 128 + ch * 4; \
    __builtin_amdgcn_global_load_lds( \
        (const __attribute__((address_space(1))) void*)g, \
        (__attribute__((address_space(3))) void*)&kst[(S) & 3][slot * 256], \
        16, 0, 0); \
  } }

#define A_LD(H, L, S) { H = A8h[((S) * 4 + kq) * 64 + lane]; \
                        L = A8l[((S) * 4 + kq) * 64 + lane]; }

#define COMP(S, H, L, ACC) { \
  float4 q0 = *(const float4*)&kst[(S) & 3][o0]; \
  float4 q1 = *(const float4*)&kst[(S) & 3][o1]; \
  float ff[8] = {q0.x, q0.y, q0.z, q0.w, q1.x, q1.y, q1.z, q1.w}; \
  short8 bh, bl; \
  _Pragma("unroll") for (int j = 0; j < 8; ++j) { \
    unsigned short hu = f2bf(ff[j]); \
    bh[j] = (short)hu; \
    float hf = __uint_as_float(((unsigned int)hu) << 16); \
    bl[j] = (short)f2bf(ff[j] - hf); \
  } \
  ACC = __builtin_amdgcn_mfma_f32_16x16x32_bf16(H, bh, ACC, 0, 0, 0); \
  ACC = __builtin_amdgcn_mfma_f32_16x16x32_bf16(H, bl, ACC, 0, 0, 0); \
  ACC = __builtin_amdgcn_mfma_f32_16x16x32_bf16(L, bh, ACC, 0, 0, 0); }

  // prologue: 3 groups in flight (group = 2 A-loads + 2 stage loads = 4 VMEM)
  A_LD(a0h, a0l, 0) STAGE(0) SB();
  A_LD(a1h, a1l, 1) STAGE(1) SB();
  A_LD(a2h, a2l, 2) STAGE(2) SB();

  // steady state: wait own group s (vmcnt 8 = 2 groups in flight), barrier
  // (all waves' slice-s loads landed), compute s, issue group s+3.
  WAITV(8); BAR(); COMP(0, a0h, a0l, acc0) A_LD(a0h, a0l, 3) STAGE(3) SB();
  WAITV(8); BAR(); COMP(1, a1h, a1l, acc1) A_LD(a1h, a1l, 4) STAGE(4) SB();
  WAITV(8); BAR(); COMP(2, a2h, a2l, acc0) A_LD(a2h, a2l, 5) STAGE(5) SB();
  WAITV(8); BAR(); COMP(3, a0h, a0l, acc1) A_LD(a0h, a0l, 6) STAGE(6) SB();
  WAITV(8); BAR(); COMP(4, a1h, a1l, acc0) A_LD(a1h, a1l, 7) STAGE(7) SB();
  WAITV(8); BAR(); COMP(5, a2h, a2l, acc1)
  WAITV(4); BAR(); COMP(6, a0h, a0l, acc0)
  WAITV(0); BAR(); COMP(7, a1h, a1l, acc1)
#undef STAGE
#undef A_LD
#undef COMP

  f32x4 at = acc0 + acc1;
  sred[wv][lane] = at;
  __syncthreads();
  if (kq == 0) {                          // waves 0 and 4 combine 4 kb-partials
    f32x4 o1v = sred[wv + 1][lane];
    f32x4 o2v = sred[wv + 2][lane];
    f32x4 o3v = sred[wv + 3][lane];
    const float4 dv = *(const float4*)(d0 + quad * 4);
    float ex0 = __expf(at[0] + o1v[0] + o2v[0] + o3v[0] + dv.x);
    float ex1 = __expf(at[1] + o1v[1] + o2v[1] + o3v[1] + dv.y);
    float ex2 = __expf(at[2] + o1v[2] + o2v[2] + o3v[2] + dv.z);
    float ex3 = __expf(at[3] + o1v[3] + o2v[3] + o3v[3] + dv.w);
    *(float4*)&el[nl * 16 + quad * 4] = make_float4(ex0, ex1, ex2, ex3);
  }
  __syncthreads();

  if (t < 16) {                           // per-chunk denominator partial
    float s = 0.f;
#pragma unroll
    for (int r = 0; r < 32; ++r) s += el[r * 16 + t];
    Spart[t * 512 + nb] = s;
  }

  // Phase B: PV. Thread owns cols 2t, 2t+1 over the 32 rows; double-buffered.
  float2 acc[16];
#pragma unroll
  for (int h = 0; h < 16; ++h) acc[h] = make_float2(0.f, 0.f);
  const float* vp = value + (size_t)(nb * 32) * DM + 2 * t;
  float2 vbA[8], vbB[8];

#define LOADV(VB, G) { _Pragma("unroll") for (int i = 0; i < 8; ++i) \
    VB[i] = *(const float2*)(vp + (size_t)((G) * 8 + i) * DM); }
#define COMPV(VB, G) { \
  _Pragma("unroll") for (int i = 0; i < 8; ++i) { \
    const float4* er4 = (const float4*)&el[((G) * 8 + i) * 16]; \
    float4 e0 = er4[0], e1 = er4[1], e2 = er4[2], e3 = er4[3]; \
    float2 vvv = VB[i]; \
    acc[0].x  = fmaf(e0.x, vvv.x, acc[0].x);  acc[0].y  = fmaf(e0.x, vvv.y, acc[0].y); \
    acc[1].x  = fmaf(e0.y, vvv.x, acc[1].x);  acc[1].y  = fmaf(e0.y, vvv.y, acc[1].y); \
    acc[2].x  = fmaf(e0.z, vvv.x, acc[2].x);  acc[2].y  = fmaf(e0.z, vvv.y, acc[2].y); \
    acc[3].x  = fmaf(e0.w, vvv.x, acc[3].x);  acc[3].y  = fmaf(e0.w, vvv.y, acc[3].y); \
    acc[4].x  = fmaf(e1.x, vvv.x, acc[4].x);  acc[4].y  = fmaf(e1.x, vvv.y, acc[4].y); \
    acc[5].x  = fmaf(e1.y, vvv.x, acc[5].x);  acc[5].y  = fmaf(e1.y, vvv.y, acc[5].y); \
    acc[6].x  = fmaf(e1.z, vvv.x, acc[6].x);  acc[6].y  = fmaf(e1.z, vvv.y, acc[6].y); \
    acc[7].x  = fmaf(e1.w, vvv.x, acc[7].x);  acc[7].y  = fmaf(e1.w, vvv.y, acc[7].y); \
    acc[8].x  = fmaf(e2.x, vvv.x, acc[8].x);  acc[8].y  = fmaf(e2.x, vvv.y, acc[8].y); \
    acc[9].x  = fmaf(e2.y, vvv.x, acc[9].x);  acc[9].y  = fmaf(e2.y, vvv.y, acc[9].y); \
    acc[10].x = fmaf(e2.z, vvv.x, acc[10].x); acc[10].y = fmaf(e2.z, vvv.y, acc[10].y); \
    acc[11].x = fmaf(e2.w, vvv.x, acc[11].x); acc[11].y = fmaf(e2.w, vvv.y, acc[11].y); \
    acc[12].x = fmaf(e3.x, vvv.x, acc[12].x); acc[12].y = fmaf(e3.x, vvv.y, acc[12].y); \
    acc[13].x = fmaf(e3.y, vvv.x, acc[13].x); acc[13].y = fmaf(e3.y, vvv.y, acc[13].y); \
    acc[14].x = fmaf(e3.z, vvv.x, acc[14].x); acc[14].y = fmaf(e3.z, vvv.y, acc[14].y); \
    acc[15].x = fmaf(e3.w, vvv.x, acc[15].x); acc[15].y = fmaf(e3.w, vvv.y, acc[15].y); \
  } }

  LOADV(vbA, 0)
  LOADV(vbB, 1)
  COMPV(vbA, 0) LOADV(vbA, 2)
  COMPV(vbB, 1) LOADV(vbB, 3)
  COMPV(vbA, 2)
  COMPV(vbB, 3)
#undef LOADV
#undef COMPV

  float* pp = part + (size_t)nb * (16 * DM) + 2 * t;
#pragma unroll
  for (int h = 0; h < 16; ++h) *(float2*)(pp + (size_t)h * DM) = acc[h];
}

// w[o] += sum over 128 chunks (4-way split across q) — fully coalesced
__global__ __launch_bounds__(256) void k_wred(const float* __restrict__ part,
                                              float* __restrict__ w) {
  const int g = blockIdx.x * 256 + threadIdx.x;  // grid 256 blocks = 65536
  const int o = g & 16383;
  const int q = g >> 14;                         // 0..3
  float s = 0.f;
#pragma unroll 1
  for (int ib = 0; ib < 16; ++ib) {
    float x[8];
#pragma unroll
    for (int j = 0; j < 8; ++j)
      x[j] = part[(size_t)(q * 128 + ib * 8 + j) * 16384 + o];
#pragma unroll
    for (int j = 0; j < 8; ++j) s += x[j];
  }
  atomicAdd(w + o, s);
}

// x[r] = dot(Wv[r,:], w[h,:]) / S[h] + bv[r],  h = r>>6 — wave per row.
// S[h] reduced in-wave from Spart[h][0..511].
__global__ __launch_bounds__(256) void k_xproj(const float* __restrict__ Wv,
                                               const float* __restrict__ w,
                                               const float* __restrict__ bv,
                                               const float* __restrict__ Spart,
                                               float* __restrict__ x) {
  const int wave = (blockIdx.x * 256 + threadIdx.x) >> 6;
  const int lane = threadIdx.x & 63;
  const int h = wave >> 6;
  const float* vec = w + (size_t)h * DM;
  const float* row = Wv + (size_t)wave * DM + 4 * lane;
  const float* sp = Spart + (size_t)h * 512;
  float s = 0.f, ss = 0.f;
#pragma unroll
  for (int i = 0; i < 8; ++i) ss += sp[i * 64 + lane];
#pragma unroll
  for (int j = 0; j < 4; ++j) {
    float4 a = *(const float4*)(row + j * 256);
    float4 x4 = *(const float4*)(vec + j * 256 + 4 * lane);
    s += a.x * x4.x + a.y * x4.y + a.z * x4.z + a.w * x4.w;
  }
#pragma unroll
  for (int off = 32; off; off >>= 1) {
    s += __shfl_xor(s, off, 64);
    ss += __shfl_xor(ss, off, 64);
  }
  if (lane == 0) x[wave] = s / ss + bv[wave];
}

extern "C" void kernel_launch(void* const* d_in, const int* in_sizes, int n_in,
                              void* d_out, int out_size, void* d_ws, size_t ws_size,
                              hipStream_t stream) {
  const float* query = (const float*)d_in[0];
  const float* key   = (const float*)d_in[1];
  const float* value = (const float*)d_in[2];
  const float* Wq    = (const float*)d_in[3];
  const float* bq    = (const float*)d_in[4];
  const float* Wk    = (const float*)d_in[5];
  const float* bk    = (const float*)d_in[6];
  const float* Wv    = (const float*)d_in[7];
  const float* bv    = (const float*)d_in[8];
  const float* Wo    = (const float*)d_in[9];
  const float* bo    = (const float*)d_in[10];
  float* out = (float*)d_out;
  float* ws  = (float*)d_ws;
  short* Ah  = (short*)(ws + OFF_AH);
  short* Al  = (short*)(ws + OFF_AL);

  k_qck    <<<64,  256, 0, stream>>>(Wq, bq, query, Wk, bk, Ah, Al,
                                     ws + OFF_D0, ws + OFF_W);
  k_spv    <<<512, 512, 0, stream>>>(key, value, Ah, Al, ws + OFF_D0,
                                     ws + OFF_PART, ws + OFF_SP);
  k_wred   <<<256, 256, 0, stream>>>(ws + OFF_PART, ws + OFF_W);
  k_xproj  <<<256, 256, 0, stream>>>(Wv, ws + OFF_W, bv, ws + OFF_SP, ws + OFF_X);
  k_rowdot <<<256, 256, 0, stream>>>(Wo, ws + OFF_X, bo, out);
}

// Round 11
// 209.115 us; speedup vs baseline: 1.0320x; 1.0320x over previous
//
#include <hip/hip_runtime.h>

#define DM 1024
#define NW 16384

typedef __attribute__((ext_vector_type(8))) short short8;
typedef __attribute__((ext_vector_type(4))) float f32x4;

// ws layout (float offsets). High-water = OFF_PART + 256*16*1024 = 4243456 floats
// (~16.2 MiB) — fits the ws buffer (256 MiB poison fills observed in rocprof).
#define OFF_AH   1024       // A-frag hi: 16384 shorts = 8192 floats
#define OFF_AL   9216       // A-frag lo: 16384 shorts
#define OFF_D0   17408      // 16
#define OFF_SP   17440      // Spart[16][256] = 4096
#define OFF_X    25632      // 1024
#define OFF_W    26656      // 16384 -> ends 43040
#define OFF_PART 49152      // part[256][16][1024] = 4194304 floats

// fp32 -> bf16 round-to-nearest-even (returns bits)
__device__ __forceinline__ unsigned short f2bf(float f) {
  unsigned int u = __float_as_uint(f);
  return (unsigned short)((u + 0x7fffu + ((u >> 16) & 1u)) >> 16);
}

// out[r] = dot(W[r,:], v) + b[r]   — one wave per row, 1024 waves
__global__ __launch_bounds__(256) void k_rowdot(const float* __restrict__ W,
                                                const float* __restrict__ v,
                                                const float* __restrict__ b,
                                                float* __restrict__ out) {
  const int wave = (blockIdx.x * 256 + threadIdx.x) >> 6;
  const int lane = threadIdx.x & 63;
  const float* row = W + (size_t)wave * DM + 4 * lane;
  float s = 0.f;
#pragma unroll
  for (int j = 0; j < 4; ++j) {
    float4 a = *(const float4*)(row + j * 256);
    float4 x = *(const float4*)(v + j * 256 + 4 * lane);
    s += a.x * x.x + a.y * x.y + a.z * x.z + a.w * x.w;
  }
#pragma unroll
  for (int off = 32; off; off >>= 1) s += __shfl_xor(s, off, 64);
  if (lane == 0) out[wave] = s + b[wave];
}

// Fused: q_h = query@Wq_h^T + bq (LDS), then c[h,m] = q_h · Wk[h*64+:,m],
// emitted directly as MFMA A-fragments (bf16 hi+lo). d0[h] = q_h·bk_h.
// Also zeroes w (16384 floats) for k_wred's atomics.
__global__ __launch_bounds__(256) void k_qck(const float* __restrict__ Wq,
                                             const float* __restrict__ bq,
                                             const float* __restrict__ query,
                                             const float* __restrict__ Wk,
                                             const float* __restrict__ bk,
                                             short* __restrict__ Ah,
                                             short* __restrict__ Al,
                                             float* __restrict__ d0,
                                             float* __restrict__ w) {
  const int h = blockIdx.x >> 2;
  const int mc = blockIdx.x & 3;
  const int t = threadIdx.x;
  const int lane = t & 63;
  const int wv = t >> 6;
  __shared__ float qh[64];
  w[blockIdx.x * 256 + t] = 0.f;          // 64*256 = 16384 threads exactly
  float4 qv[4];
#pragma unroll
  for (int j = 0; j < 4; ++j) qv[j] = *(const float4*)(query + j * 256 + 4 * lane);
#pragma unroll 1
  for (int ii = 0; ii < 16; ii += 4) {
    float4 a[4][4];
#pragma unroll
    for (int r = 0; r < 4; ++r) {
      const float* rp = Wq + (size_t)(h * 64 + 4 * (ii + r) + wv) * DM + 4 * lane;
#pragma unroll
      for (int j = 0; j < 4; ++j) a[r][j] = *(const float4*)(rp + j * 256);
    }
    float s[4] = {0.f, 0.f, 0.f, 0.f};
#pragma unroll
    for (int r = 0; r < 4; ++r)
#pragma unroll
      for (int j = 0; j < 4; ++j)
        s[r] += a[r][j].x * qv[j].x + a[r][j].y * qv[j].y +
                a[r][j].z * qv[j].z + a[r][j].w * qv[j].w;
#pragma unroll
    for (int off = 32; off; off >>= 1)
#pragma unroll
      for (int r = 0; r < 4; ++r) s[r] += __shfl_xor(s[r], off, 64);
    if (lane == 0)
#pragma unroll
      for (int r = 0; r < 4; ++r)
        qh[4 * (ii + r) + wv] = s[r] + bq[h * 64 + 4 * (ii + r) + wv];
  }
  __syncthreads();
  const int m = mc * 256 + t;
  const float* Wp = Wk + (size_t)(h * 64) * DM + m;
  float s = 0.f;
#pragma unroll 2
  for (int db = 0; db < 8; ++db) {
    float wv8[8];
#pragma unroll
    for (int j = 0; j < 8; ++j) wv8[j] = Wp[(size_t)(db * 8 + j) * DM];
#pragma unroll
    for (int j = 0; j < 8; ++j) s = fmaf(qh[db * 8 + j], wv8[j], s);
  }
  unsigned short hu = f2bf(s);
  float hf = __uint_as_float(((unsigned int)hu) << 16);
  unsigned short lu = f2bf(s - hf);
  const int kb = m >> 5, q = (m >> 3) & 3, j = m & 7;
  const int idx = (kb * 64 + q * 16 + h) * 8 + j;
  Ah[idx] = (short)hu;
  Al[idx] = (short)lu;
  if (mc == 0 && t == 0) {
    float tt = 0.f;
    for (int d = 0; d < 64; ++d) tt += qh[d] * bk[h * 64 + d];
    d0[h] = tt;
  }
}

// Fused scores + PV. 256 blocks × 512 threads (8 waves), one 64-row chunk per
// block processed as TWO sequential 32-row halves with the PV accumulator
// carried across halves — halves part traffic (32->16 MB write, and k_wred's
// re-read likewise). Per half: r9's structure verbatim (8 waves = 2 tiles ×
// 4-way K-split, direct global reads, no hot-loop barriers).
__global__ __launch_bounds__(512, 2) void k_spv(const float* __restrict__ key,
                                                const float* __restrict__ value,
                                                const short* __restrict__ AhG,
                                                const short* __restrict__ AlG,
                                                const float* __restrict__ d0,
                                                float* __restrict__ part,
                                                float* __restrict__ Spart) {
  const int nb = blockIdx.x;              // 0..255 (64-row chunk)
  const int t = threadIdx.x;              // 0..511
  const int lane = t & 63;
  const int wv = t >> 6;                  // 0..7
  const int tile = wv >> 2;               // 0..1  -> 16-row tile (within half)
  const int kq = wv & 3;                  // 4-way K-split
  const int row16 = lane & 15;
  const int nl = tile * 16 + row16;       // local row 0..31 (within half)
  const int quad = lane >> 4;
  const short8* A8h = (const short8*)AhG;
  const short8* A8l = (const short8*)AlG;
  __shared__ float el[32 * 16];           // 2 KB
  __shared__ f32x4 sred[8][64];           // 8 KB

  float2 acc[16];
#pragma unroll
  for (int h = 0; h < 16; ++h) acc[h] = make_float2(0.f, 0.f);
  float spacc = 0.f;

#pragma unroll 1
  for (int ha = 0; ha < 2; ++ha) {
    const int n = nb * 64 + ha * 32 + nl;
    const float* base = key + (size_t)n * DM + quad * 8;

    short8 ah[2][4], al[2][4];
    float4 f0[2][4], f1[2][4];
    f32x4 acc0 = {0.f, 0.f, 0.f, 0.f};
    f32x4 acc1 = {0.f, 0.f, 0.f, 0.f};

#define LOADG(buf, g) { \
  _Pragma("unroll") for (int i = 0; i < 4; ++i) { \
    const int kb = kq * 8 + (g) * 4 + i; \
    ah[buf][i] = A8h[kb * 64 + lane]; \
    al[buf][i] = A8l[kb * 64 + lane]; \
    f0[buf][i] = *(const float4*)(base + kb * 32); \
    f1[buf][i] = *(const float4*)(base + kb * 32 + 4); \
  } }

#define PROC(buf) { \
  _Pragma("unroll") for (int i = 0; i < 4; ++i) { \
    float ff[8] = {f0[buf][i].x, f0[buf][i].y, f0[buf][i].z, f0[buf][i].w, \
                   f1[buf][i].x, f1[buf][i].y, f1[buf][i].z, f1[buf][i].w}; \
    short8 bh, bl; \
    _Pragma("unroll") for (int j = 0; j < 8; ++j) { \
      unsigned short hu = f2bf(ff[j]); \
      bh[j] = (short)hu; \
      float hf = __uint_as_float(((unsigned int)hu) << 16); \
      bl[j] = (short)f2bf(ff[j] - hf); \
    } \
    if ((i & 1) == 0) { \
      acc0 = __builtin_amdgcn_mfma_f32_16x16x32_bf16(ah[buf][i], bh, acc0, 0, 0, 0); \
      acc0 = __builtin_amdgcn_mfma_f32_16x16x32_bf16(ah[buf][i], bl, acc0, 0, 0, 0); \
      acc0 = __builtin_amdgcn_mfma_f32_16x16x32_bf16(al[buf][i], bh, acc0, 0, 0, 0); \
    } else { \
      acc1 = __builtin_amdgcn_mfma_f32_16x16x32_bf16(ah[buf][i], bh, acc1, 0, 0, 0); \
      acc1 = __builtin_amdgcn_mfma_f32_16x16x32_bf16(ah[buf][i], bl, acc1, 0, 0, 0); \
      acc1 = __builtin_amdgcn_mfma_f32_16x16x32_bf16(al[buf][i], bh, acc1, 0, 0, 0); \
    } \
  } }

    LOADG(0, 0)
    LOADG(1, 1)
    PROC(0)
    PROC(1)
#undef LOADG
#undef PROC

    f32x4 at = acc0 + acc1;
    sred[wv][lane] = at;
    __syncthreads();
    if (kq == 0) {                        // waves 0 and 4 combine 4 K-partials
      f32x4 o1 = sred[wv + 1][lane];
      f32x4 o2 = sred[wv + 2][lane];
      f32x4 o3 = sred[wv + 3][lane];
      const float4 dv = *(const float4*)(d0 + quad * 4);
      float ex0 = __expf(at[0] + o1[0] + o2[0] + o3[0] + dv.x);
      float ex1 = __expf(at[1] + o1[1] + o2[1] + o3[1] + dv.y);
      float ex2 = __expf(at[2] + o1[2] + o2[2] + o3[2] + dv.z);
      float ex3 = __expf(at[3] + o1[3] + o2[3] + o3[3] + dv.w);
      *(float4*)&el[nl * 16 + quad * 4] = make_float4(ex0, ex1, ex2, ex3);
    }
    __syncthreads();

    if (t < 16) {                         // per-half denominator partial
      float s = 0.f;
#pragma unroll
      for (int r = 0; r < 32; ++r) s += el[r * 16 + t];
      spacc += s;
    }

    // Phase B: PV for this half. Thread owns cols 2t, 2t+1; 2-deep dbuf.
    const float* vp = value + (size_t)(nb * 64 + ha * 32) * DM + 2 * t;
    float2 vbA[8], vbB[8];

#define LOADV(VB, G) { _Pragma("unroll") for (int i = 0; i < 8; ++i) \
    VB[i] = *(const float2*)(vp + (size_t)((G) * 8 + i) * DM); }
#define COMPV(VB, G) { \
  _Pragma("unroll") for (int i = 0; i < 8; ++i) { \
    const float4* er4 = (const float4*)&el[((G) * 8 + i) * 16]; \
    float4 e0 = er4[0], e1 = er4[1], e2 = er4[2], e3 = er4[3]; \
    float2 vvv = VB[i]; \
    acc[0].x  = fmaf(e0.x, vvv.x, acc[0].x);  acc[0].y  = fmaf(e0.x, vvv.y, acc[0].y); \
    acc[1].x  = fmaf(e0.y, vvv.x, acc[1].x);  acc[1].y  = fmaf(e0.y, vvv.y, acc[1].y); \
    acc[2].x  = fmaf(e0.z, vvv.x, acc[2].x);  acc[2].y  = fmaf(e0.z, vvv.y, acc[2].y); \
    acc[3].x  = fmaf(e0.w, vvv.x, acc[3].x);  acc[3].y  = fmaf(e0.w, vvv.y, acc[3].y); \
    acc[4].x  = fmaf(e1.x, vvv.x, acc[4].x);  acc[4].y  = fmaf(e1.x, vvv.y, acc[4].y); \
    acc[5].x  = fmaf(e1.y, vvv.x, acc[5].x);  acc[5].y  = fmaf(e1.y, vvv.y, acc[5].y); \
    acc[6].x  = fmaf(e1.z, vvv.x, acc[6].x);  acc[6].y  = fmaf(e1.z, vvv.y, acc[6].y); \
    acc[7].x  = fmaf(e1.w, vvv.x, acc[7].x);  acc[7].y  = fmaf(e1.w, vvv.y, acc[7].y); \
    acc[8].x  = fmaf(e2.x, vvv.x, acc[8].x);  acc[8].y  = fmaf(e2.x, vvv.y, acc[8].y); \
    acc[9].x  = fmaf(e2.y, vvv.x, acc[9].x);  acc[9].y  = fmaf(e2.y, vvv.y, acc[9].y); \
    acc[10].x = fmaf(e2.z, vvv.x, acc[10].x); acc[10].y = fmaf(e2.z, vvv.y, acc[10].y); \
    acc[11].x = fmaf(e2.w, vvv.x, acc[11].x); acc[11].y = fmaf(e2.w, vvv.y, acc[11].y); \
    acc[12].x = fmaf(e3.x, vvv.x, acc[12].x); acc[12].y = fmaf(e3.x, vvv.y, acc[12].y); \
    acc[13].x = fmaf(e3.y, vvv.x, acc[13].x); acc[13].y = fmaf(e3.y, vvv.y, acc[13].y); \
    acc[14].x = fmaf(e3.z, vvv.x, acc[14].x); acc[14].y = fmaf(e3.z, vvv.y, acc[14].y); \
    acc[15].x = fmaf(e3.w, vvv.x, acc[15].x); acc[15].y = fmaf(e3.w, vvv.y, acc[15].y); \
  } }

    LOADV(vbA, 0)
    LOADV(vbB, 1)
    COMPV(vbA, 0) LOADV(vbA, 2)
    COMPV(vbB, 1) LOADV(vbB, 3)
    COMPV(vbA, 2)
    COMPV(vbB, 3)
#undef LOADV
#undef COMPV

    __syncthreads();                      // el/sred reuse safety for next half
  }

  if (t < 16) Spart[t * 256 + nb] = spacc;

  float* pp = part + (size_t)nb * (16 * DM) + 2 * t;
#pragma unroll
  for (int h = 0; h < 16; ++h) *(float2*)(pp + (size_t)h * DM) = acc[h];
}

// w[o] += sum over 64 chunks (4-way split across q) — fully coalesced
__global__ __launch_bounds__(256) void k_wred(const float* __restrict__ part,
                                              float* __restrict__ w) {
  const int g = blockIdx.x * 256 + threadIdx.x;  // grid 256 blocks = 65536
  const int o = g & 16383;
  const int q = g >> 14;                         // 0..3
  float s = 0.f;
#pragma unroll 1
  for (int ib = 0; ib < 8; ++ib) {
    float x[8];
#pragma unroll
    for (int j = 0; j < 8; ++j)
      x[j] = part[(size_t)(q * 64 + ib * 8 + j) * 16384 + o];
#pragma unroll
    for (int j = 0; j < 8; ++j) s += x[j];
  }
  atomicAdd(w + o, s);
}

// x[r] = dot(Wv[r,:], w[h,:]) / S[h] + bv[r],  h = r>>6 — wave per row.
// S[h] reduced in-wave from Spart[h][0..255].
__global__ __launch_bounds__(256) void k_xproj(const float* __restrict__ Wv,
                                               const float* __restrict__ w,
                                               const float* __restrict__ bv,
                                               const float* __restrict__ Spart,
                                               float* __restrict__ x) {
  const int wave = (blockIdx.x * 256 + threadIdx.x) >> 6;
  const int lane = threadIdx.x & 63;
  const int h = wave >> 6;
  const float* vec = w + (size_t)h * DM;
  const float* row = Wv + (size_t)wave * DM + 4 * lane;
  const float* sp = Spart + (size_t)h * 256;
  float s = 0.f, ss = 0.f;
#pragma unroll
  for (int i = 0; i < 4; ++i) ss += sp[i * 64 + lane];
#pragma unroll
  for (int j = 0; j < 4; ++j) {
    float4 a = *(const float4*)(row + j * 256);
    float4 x4 = *(const float4*)(vec + j * 256 + 4 * lane);
    s += a.x * x4.x + a.y * x4.y + a.z * x4.z + a.w * x4.w;
  }
#pragma unroll
  for (int off = 32; off; off >>= 1) {
    s += __shfl_xor(s, off, 64);
    ss += __shfl_xor(ss, off, 64);
  }
  if (lane == 0) x[wave] = s / ss + bv[wave];
}

extern "C" void kernel_launch(void* const* d_in, const int* in_sizes, int n_in,
                              void* d_out, int out_size, void* d_ws, size_t ws_size,
                              hipStream_t stream) {
  const float* query = (const float*)d_in[0];
  const float* key   = (const float*)d_in[1];
  const float* value = (const float*)d_in[2];
  const float* Wq    = (const float*)d_in[3];
  const float* bq    = (const float*)d_in[4];
  const float* Wk    = (const float*)d_in[5];
  const float* bk    = (const float*)d_in[6];
  const float* Wv    = (const float*)d_in[7];
  const float* bv    = (const float*)d_in[8];
  const float* Wo    = (const float*)d_in[9];
  const float* bo    = (const float*)d_in[10];
  float* out = (float*)d_out;
  float* ws  = (float*)d_ws;
  short* Ah  = (short*)(ws + OFF_AH);
  short* Al  = (short*)(ws + OFF_AL);

  k_qck    <<<64,  256, 0, stream>>>(Wq, bq, query, Wk, bk, Ah, Al,
                                     ws + OFF_D0, ws + OFF_W);
  k_spv    <<<256, 512, 0, stream>>>(key, value, Ah, Al, ws + OFF_D0,
                                     ws + OFF_PART, ws + OFF_SP);
  k_wred   <<<256, 256, 0, stream>>>(ws + OFF_PART, ws + OFF_W);
  k_xproj  <<<256, 256, 0, stream>>>(Wv, ws + OFF_W, bv, ws + OFF_SP, ws + OFF_X);
  k_rowdot <<<256, 256, 0, stream>>>(Wo, ws + OFF_X, bo, out);
}